// Round 3
// baseline (520.326 us; speedup 1.0000x reference)
//
#include <hip/hip_runtime.h>
#include <hip/hip_bf16.h>
#include <math.h>

// MFGN forward, MI355X. One block (512 thr, 8 waves) per outfit.
// R16: LDS-THROUGHPUT diet. Evidence: R13(74KB,3barr) == R15(54KB,4barr,
// +swizzle VALU) == 237us, conflicts equal -> not occupancy/barrier/VALU
// bound; LDS pipe ~60%+ busy (3.8MB/block traffic + 3.1e7 conflict cy).
// Changes vs R13 structure:
//  - Phase B/C wave re-tiling: wave owns (mt-pair x 32 cols) instead of
//    (all 4 mt x 16 cols): each prod/hid fragment read feeds 2 MFMAs ->
//    L1/L2 LDS reads halved (the dominant traffic term).
//    B epilogue's cross-wave row-sum via ds_add_f32 atomicAdd (no new barrier).
//  - Phase D: featB A-fragments cached in regs across u-loop; only lanes
//    n16==iv reload after the row update (-200KB/block).
//  - Phase F: G symmetric -> compute f<=g only, x2 off-diag (-200KB/block).
//  - Back to separate prodS/hidS (3 barriers/step), padded strides, no
//    swizzle (R15 proved swizzle==pad for conflicts; LDS size free at 2 blk).
//  - launch_bounds(512,2): reg cap 128 for the +64 weight VGPRs (2 col-tiles).
// R13 heritage: lrelu=fmax(x,.01x), bias-in-acc init, no conditional acc defs.

typedef __attribute__((ext_vector_type(8))) short short8;
typedef __attribute__((ext_vector_type(4))) float f32x4;

#define MFMA16(a, b, c) __builtin_amdgcn_mfma_f32_16x16x32_bf16(a, b, c, 0, 0, 0)

__device__ __forceinline__ float lrelu(float x) { return fmaxf(x, 0.01f * x); }

__device__ __forceinline__ ushort f2bf(float f) {
  unsigned u = __builtin_bit_cast(unsigned, f);
  u += 0x7fffu + ((u >> 16) & 1u);  // RNE
  return (ushort)(u >> 16);
}
__device__ __forceinline__ float bflo(unsigned u) {
  return __builtin_bit_cast(float, u << 16);
}
__device__ __forceinline__ unsigned pk2(float a, float b) {
  float2 t; t.x = a; t.y = b;
  __hip_bfloat162 h = __float22bfloat162_rn(t);
  unsigned u;
  __builtin_memcpy(&u, &h, 4);
  return u;
}

// d_ws layout (ushort): cfW1T@0 [4][64n][128k] | cfW2T@32768 [4][128n][64k]
// | f2fW1T@65536 | f2fW2T@81920 | f2iW1T@98304 | f2iW2T@114688
// | i2iW1T@131072 | i2iW2T@147456   ([128n][128k] each; 320KB total)

__global__ __launch_bounds__(256) void prep_weights(
    const float* __restrict__ cfW1, const float* __restrict__ cfW2,
    const float* __restrict__ f2fW1, const float* __restrict__ f2fW2,
    const float* __restrict__ f2iW1, const float* __restrict__ f2iW2,
    const float* __restrict__ i2iW1, const float* __restrict__ i2iW2,
    ushort* __restrict__ ws, float* __restrict__ out) {
  const int idx = (int)(blockIdx.x * 256 + threadIdx.x);
  if (idx == 0) out[2048] = 0.0f;  // com accumulator zero
  float v;
  if (idx < 32768) {          // cfW1 [f][k<128][n<64] -> [f][n][k]
    int f = idx >> 13, r = idx & 8191, n = r >> 7, k = r & 127;
    v = cfW1[f * 8192 + k * 64 + n];
  } else if (idx < 65536) {   // cfW2 [f][k<64][n<128] -> [f][n][k]
    int t = idx - 32768;
    int f = t >> 13, r = t & 8191, n = r >> 6, k = r & 63;
    v = cfW2[f * 8192 + k * 128 + n];
  } else {                    // 6 x [k<128][n<128] -> [n][k]
    int t = idx - 65536;
    int seg = t >> 14, r = t & 16383, n = r >> 7, k = r & 127;
    const float* W = (seg == 0) ? f2fW1 : (seg == 1) ? f2fW2 :
                     (seg == 2) ? f2iW1 : (seg == 3) ? f2iW2 :
                     (seg == 4) ? i2iW1 : i2iW2;
    v = W[k * 128 + n];
  }
  ws[idx] = f2bf(v);
}

__global__ __launch_bounds__(512, 2) void mfgn_kernel(
    const int* __restrict__ outfit_items,
    const float* __restrict__ items_feature,
    const int* __restrict__ items_neighbor,
    const float* __restrict__ cfb1, const float* __restrict__ cfb2,
    const float* __restrict__ f2fb1, const float* __restrict__ f2fb2,
    const float* __restrict__ f2ib1, const float* __restrict__ f2ib2,
    const float* __restrict__ i2ib1, const float* __restrict__ i2ib2,
    const float* __restrict__ o2sW, const float* __restrict__ o2sb,
    const ushort* __restrict__ wsW,
    float* __restrict__ out)
{
  __shared__ float facL[16 * 528];                                 // 33792 B fp32 state
  __shared__ ushort prodS[64 * 136] __attribute__((aligned(16)));  // 17408 B bf16 A-staging
  __shared__ ushort hidS[64 * 136] __attribute__((aligned(16)));   // 17408 B bf16 hidden
  __shared__ ushort featB[16 * 136] __attribute__((aligned(16)));  //  4352 B bf16 feat state
  __shared__ float redE[8];
  __shared__ int oiL[16];
  __shared__ int clAll[256];
  __shared__ int ncAll[16];
  __shared__ int vslL[16];
  __shared__ int refcntL[16];
  __shared__ int nvsL;

  const int o = blockIdx.x;
  const int tid = (int)threadIdx.x;
  const int lane = tid & 63;
  const int wid = tid >> 6;
  const int n16 = lane & 15;
  const int q = lane >> 4;
  const int kb = q * 8;
  const int col = wid * 16 + n16;          // Phase A/D col ownership
  // Phase B/C re-tiled ownership: wave = (mtp row-pair, colp 32-col group)
  const int colp = wid & 3, mtp = wid >> 2;
  const int cb0 = colp * 32;

  // ---------------- load inputs ----------------
  if (tid < 16) oiL[tid] = outfit_items[o * 16 + tid];
  {
    const int n = tid >> 5, d0 = (tid & 31) * 4;
    float4 v = *(const float4*)(items_feature + o * 2048 + tid * 4);
    uint2 pk; pk.x = pk2(v.x, v.y); pk.y = pk2(v.z, v.w);
    *(uint2*)(featB + n * 136 + d0) = pk;
  }
  if (tid == 0) {
    int cnt = 0;
    for (int s = 0; s < 16; ++s) refcntL[s] = 0;
    for (int s = 0; s < 16; ++s) {
      int v = oiL[s];
      if (v != -1) { vslL[cnt++] = s; refcntL[v]++; }
    }
    nvsL = cnt;
  }
  for (int s = wid; s < 16; s += 8) {
    const int iv = outfit_items[o * 16 + s];
    if (iv == -1) { if (lane == 0) ncAll[s] = 0; continue; }
    int cand = -1;
    if (lane < 24) cand = (lane < 16) ? outfit_items[o * 16 + lane]
                                      : items_neighbor[o * 128 + iv * 8 + (lane - 16)];
    bool ok = (lane < 24) && (cand != -1) && (cand != iv);
    unsigned long long bm = __ballot(ok);
    if (ok) clAll[s * 16 + __popcll(bm & ((1ull << lane) - 1ull))] = cand;
    if (lane == 0) ncAll[s] = (int)__popcll(bm);
  }
  __syncthreads();
  const int nvs = nvsL;

  // ---------------- Phase A: creat_factors (unchanged structure) ----------------
  {
    const int f = wid & 3, half = wid >> 2;
    short8 wA[2][4];
#pragma unroll
    for (int etl = 0; etl < 2; ++etl)
#pragma unroll
      for (int kt = 0; kt < 4; ++kt)
        wA[etl][kt] = *(const short8*)(wsW + (f * 64 + (half * 2 + etl) * 16 + n16) * 128
                                       + kt * 32 + kb);
    f32x4 acc[2];
#pragma unroll
    for (int etl = 0; etl < 2; ++etl)
      acc[etl] = *(const f32x4*)(cfb1 + f * 64 + (half * 2 + etl) * 16 + q * 4);
    for (int kt = 0; kt < 4; ++kt) {
      short8 x = *(const short8*)(featB + n16 * 136 + kt * 32 + kb);
      acc[0] = MFMA16(wA[0][kt], x, acc[0]);
      acc[1] = MFMA16(wA[1][kt], x, acc[1]);
    }
#pragma unroll
    for (int etl = 0; etl < 2; ++etl) {
      float h0 = lrelu(acc[etl][0]), h1 = lrelu(acc[etl][1]);
      float h2 = lrelu(acc[etl][2]), h3 = lrelu(acc[etl][3]);
      uint2 pk; pk.x = pk2(h0, h1); pk.y = pk2(h2, h3);
      *(uint2*)(hidS + (f * 16 + n16) * 136 + (half * 2 + etl) * 16 + q * 4) = pk;
    }
    __syncthreads();
    short8 wB[4][2];
#pragma unroll
    for (int ctl = 0; ctl < 4; ++ctl)
#pragma unroll
      for (int kt = 0; kt < 2; ++kt)
        wB[ctl][kt] = *(const short8*)(wsW + 32768 + (f * 128 + half * 64 + ctl * 16 + n16) * 64
                                       + kt * 32 + kb);
    f32x4 acc2[4];
#pragma unroll
    for (int ctl = 0; ctl < 4; ++ctl) {
      float b2 = cfb2[f * 128 + half * 64 + ctl * 16 + n16];
      acc2[ctl] = (f32x4){b2, b2, b2, b2};
    }
    for (int kt = 0; kt < 2; ++kt) {
      short8 h = *(const short8*)(hidS + (f * 16 + n16) * 136 + kt * 32 + kb);
#pragma unroll
      for (int ctl = 0; ctl < 4; ++ctl) acc2[ctl] = MFMA16(h, wB[ctl][kt], acc2[ctl]);
    }
#pragma unroll
    for (int ctl = 0; ctl < 4; ++ctl) {
      int c = half * 64 + ctl * 16 + n16;
#pragma unroll
      for (int r = 0; r < 4; ++r)
        facL[(q * 4 + r) * 528 + f * 132 + c] = lrelu(acc2[ctl][r]);
    }
    __syncthreads();
  }

  // ---------------- Phase B: inter_factors (re-tiled: mt-pair x 32 cols) ----------------
  {
    short8 w1f[2][4], w2f[2][4];
#pragma unroll
    for (int c2 = 0; c2 < 2; ++c2)
#pragma unroll
      for (int kt = 0; kt < 4; ++kt) {
        w1f[c2][kt] = *(const short8*)(wsW + 65536 + (cb0 + c2 * 16 + n16) * 128 + kt * 32 + kb);
        w2f[c2][kt] = *(const short8*)(wsW + 81920 + (cb0 + c2 * 16 + n16) * 128 + kt * 32 + kb);
      }
    f32x4 b1q[2];
    float b2v[2];
#pragma unroll
    for (int c2 = 0; c2 < 2; ++c2) {
      b1q[c2] = *(const f32x4*)(f2fb1 + cb0 + c2 * 16 + q * 4);
      b2v[c2] = f2fb2[cb0 + c2 * 16 + n16];
    }
    const int rS = tid >> 3, kcS = tid & 7;   // staging: row, 16-value k-chunk
    const int fS = rS & 3, ciS = rS >> 2;
    const int k0 = kcS * 16;

    for (int u = 0; u < nvs; ++u) {
      const int s = vslL[u];
      const int iv = oiL[s];
      const int nc = ncAll[s];
      // stage prod[r=ci*4+f][k] = bf16(fac[iv][f][k] * fac[cand][f][k])
      // rows >= 4*nc stale (finite bf16, epilogue-masked; MLP row-separable)
      if (ciS < nc) {
        const int cit = clAll[s * 16 + ciS];
        const float* tp = facL + iv * 528 + fS * 132;
        const float* cp = facL + cit * 528 + fS * 132;
#pragma unroll
        for (int i2 = 0; i2 < 2; ++i2) {
          const int k = k0 + i2 * 8;
          float4 a0 = *(const float4*)(tp + k), a1 = *(const float4*)(tp + k + 4);
          float4 c0 = *(const float4*)(cp + k), c1 = *(const float4*)(cp + k + 4);
          uint4 u4;
          u4.x = pk2(a0.x * c0.x, a0.y * c0.y); u4.y = pk2(a0.z * c0.z, a0.w * c0.w);
          u4.z = pk2(a1.x * c1.x, a1.y * c1.y); u4.w = pk2(a1.z * c1.z, a1.w * c1.w);
          *(uint4*)(prodS + rS * 136 + k) = u4;
        }
      }
      __syncthreads();  // [b1] products ready
      // L1 swapped: 8 fragment reads feed 16 MFMA (2x reuse)
      f32x4 acc00 = b1q[0], acc01 = b1q[1], acc10 = b1q[0], acc11 = b1q[1];
      for (int kt = 0; kt < 4; ++kt) {
        short8 x0 = *(const short8*)(prodS + (mtp * 32 + n16) * 136 + kt * 32 + kb);
        short8 x1 = *(const short8*)(prodS + (mtp * 32 + 16 + n16) * 136 + kt * 32 + kb);
        acc00 = MFMA16(w1f[0][kt], x0, acc00);
        acc01 = MFMA16(w1f[1][kt], x0, acc01);
        acc10 = MFMA16(w1f[0][kt], x1, acc10);
        acc11 = MFMA16(w1f[1][kt], x1, acc11);
      }
      // hid store: (mt2,c2) -> row mtp*32+mt2*16+n16, col cb0+c2*16+q*4
      {
        uint2 pk;
        pk.x = pk2(lrelu(acc00[0]), lrelu(acc00[1])); pk.y = pk2(lrelu(acc00[2]), lrelu(acc00[3]));
        *(uint2*)(hidS + (mtp * 32 + n16) * 136 + cb0 + q * 4) = pk;
        pk.x = pk2(lrelu(acc01[0]), lrelu(acc01[1])); pk.y = pk2(lrelu(acc01[2]), lrelu(acc01[3]));
        *(uint2*)(hidS + (mtp * 32 + n16) * 136 + cb0 + 16 + q * 4) = pk;
        pk.x = pk2(lrelu(acc10[0]), lrelu(acc10[1])); pk.y = pk2(lrelu(acc10[2]), lrelu(acc10[3]));
        *(uint2*)(hidS + (mtp * 32 + 16 + n16) * 136 + cb0 + q * 4) = pk;
        pk.x = pk2(lrelu(acc11[0]), lrelu(acc11[1])); pk.y = pk2(lrelu(acc11[2]), lrelu(acc11[3]));
        *(uint2*)(hidS + (mtp * 32 + 16 + n16) * 136 + cb0 + 16 + q * 4) = pk;
      }
      __syncthreads();  // [b2] hid ready
      // L2: 8 fragment reads feed 16 MFMA
      f32x4 a200 = (f32x4){b2v[0], b2v[0], b2v[0], b2v[0]};
      f32x4 a201 = (f32x4){b2v[1], b2v[1], b2v[1], b2v[1]};
      f32x4 a210 = (f32x4){b2v[0], b2v[0], b2v[0], b2v[0]};
      f32x4 a211 = (f32x4){b2v[1], b2v[1], b2v[1], b2v[1]};
      for (int kt = 0; kt < 4; ++kt) {
        short8 h0 = *(const short8*)(hidS + (mtp * 32 + n16) * 136 + kt * 32 + kb);
        short8 h1 = *(const short8*)(hidS + (mtp * 32 + 16 + n16) * 136 + kt * 32 + kb);
        a200 = MFMA16(h0, w2f[0][kt], a200);
        a201 = MFMA16(h0, w2f[1][kt], a201);
        a210 = MFMA16(h1, w2f[0][kt], a210);
        a211 = MFMA16(h1, w2f[1][kt], a211);
      }
      // epilogue: ci = mtp*8 + mt2*4 + q; sum masked rows; q-reduce; atomic add
      const bool act0 = (mtp * 8 + q) < nc;
      const bool act1 = (mtp * 8 + 4 + q) < nc;
      float pr[2][4];
#pragma unroll
      for (int c2 = 0; c2 < 2; ++c2)
#pragma unroll
        for (int r = 0; r < 4; ++r) pr[c2][r] = 0.f;
      if (act0) {
#pragma unroll
        for (int r = 0; r < 4; ++r) { pr[0][r] += lrelu(a200[r]); pr[1][r] += lrelu(a201[r]); }
      }
      if (act1) {
#pragma unroll
        for (int r = 0; r < 4; ++r) { pr[0][r] += lrelu(a210[r]); pr[1][r] += lrelu(a211[r]); }
      }
#pragma unroll
      for (int c2 = 0; c2 < 2; ++c2)
#pragma unroll
        for (int r = 0; r < 4; ++r) {
          float v = pr[c2][r];
          v += __shfl_xor(v, 16);
          v += __shfl_xor(v, 32);
          pr[c2][r] = v;
        }
      if (q == 0) {  // two waves (mtp=0,1) share cols -> ds_add_f32
#pragma unroll
        for (int c2 = 0; c2 < 2; ++c2)
#pragma unroll
          for (int r = 0; r < 4; ++r)
            atomicAdd(&facL[iv * 528 + r * 132 + cb0 + c2 * 16 + n16], pr[c2][r]);
      }
      __syncthreads();  // [b3] facL updated for next step's stage
    }
  }

  // ---------------- Phase C: infer_items (re-tiled like B) ----------------
  {
    short8 w1f[2][4], w2f[2][4];
#pragma unroll
    for (int c2 = 0; c2 < 2; ++c2)
#pragma unroll
      for (int kt = 0; kt < 4; ++kt) {
        w1f[c2][kt] = *(const short8*)(wsW + 98304 + (cb0 + c2 * 16 + n16) * 128 + kt * 32 + kb);
        w2f[c2][kt] = *(const short8*)(wsW + 114688 + (cb0 + c2 * 16 + n16) * 128 + kt * 32 + kb);
      }
    f32x4 b1q[2];
    float b2v[2];
#pragma unroll
    for (int c2 = 0; c2 < 2; ++c2) {
      b1q[c2] = *(const f32x4*)(f2ib1 + cb0 + c2 * 16 + q * 4);
      b2v[c2] = f2ib2[cb0 + c2 * 16 + n16];
    }
    // stage prod[r=item*4+f][k] = bf16(fac[item][f][k]); all 64 rows
    {
      const int r = tid >> 3, kc = tid & 7, k0 = kc * 16;
      const int f = r & 3, item = r >> 2;
      const float* sp = facL + item * 528 + f * 132;
#pragma unroll
      for (int i2 = 0; i2 < 2; ++i2) {
        const int k = k0 + i2 * 8;
        float4 a0 = *(const float4*)(sp + k), a1 = *(const float4*)(sp + k + 4);
        uint4 u;
        u.x = pk2(a0.x, a0.y); u.y = pk2(a0.z, a0.w);
        u.z = pk2(a1.x, a1.y); u.w = pk2(a1.z, a1.w);
        *(uint4*)(prodS + r * 136 + k) = u;
      }
    }
    __syncthreads();
    f32x4 acc00 = b1q[0], acc01 = b1q[1], acc10 = b1q[0], acc11 = b1q[1];
    for (int kt = 0; kt < 4; ++kt) {
      short8 x0 = *(const short8*)(prodS + (mtp * 32 + n16) * 136 + kt * 32 + kb);
      short8 x1 = *(const short8*)(prodS + (mtp * 32 + 16 + n16) * 136 + kt * 32 + kb);
      acc00 = MFMA16(w1f[0][kt], x0, acc00);
      acc01 = MFMA16(w1f[1][kt], x0, acc01);
      acc10 = MFMA16(w1f[0][kt], x1, acc10);
      acc11 = MFMA16(w1f[1][kt], x1, acc11);
    }
    {
      uint2 pk;
      pk.x = pk2(lrelu(acc00[0]), lrelu(acc00[1])); pk.y = pk2(lrelu(acc00[2]), lrelu(acc00[3]));
      *(uint2*)(hidS + (mtp * 32 + n16) * 136 + cb0 + q * 4) = pk;
      pk.x = pk2(lrelu(acc01[0]), lrelu(acc01[1])); pk.y = pk2(lrelu(acc01[2]), lrelu(acc01[3]));
      *(uint2*)(hidS + (mtp * 32 + n16) * 136 + cb0 + 16 + q * 4) = pk;
      pk.x = pk2(lrelu(acc10[0]), lrelu(acc10[1])); pk.y = pk2(lrelu(acc10[2]), lrelu(acc10[3]));
      *(uint2*)(hidS + (mtp * 32 + 16 + n16) * 136 + cb0 + q * 4) = pk;
      pk.x = pk2(lrelu(acc11[0]), lrelu(acc11[1])); pk.y = pk2(lrelu(acc11[2]), lrelu(acc11[3]));
      *(uint2*)(hidS + (mtp * 32 + 16 + n16) * 136 + cb0 + 16 + q * 4) = pk;
    }
    __syncthreads();
    f32x4 a200 = (f32x4){b2v[0], b2v[0], b2v[0], b2v[0]};
    f32x4 a201 = (f32x4){b2v[1], b2v[1], b2v[1], b2v[1]};
    f32x4 a210 = (f32x4){b2v[0], b2v[0], b2v[0], b2v[0]};
    f32x4 a211 = (f32x4){b2v[1], b2v[1], b2v[1], b2v[1]};
    for (int kt = 0; kt < 4; ++kt) {
      short8 h0 = *(const short8*)(hidS + (mtp * 32 + n16) * 136 + kt * 32 + kb);
      short8 h1 = *(const short8*)(hidS + (mtp * 32 + 16 + n16) * 136 + kt * 32 + kb);
      a200 = MFMA16(h0, w2f[0][kt], a200);
      a201 = MFMA16(h0, w2f[1][kt], a201);
      a210 = MFMA16(h1, w2f[0][kt], a210);
      a211 = MFMA16(h1, w2f[1][kt], a211);
    }
    // epilogue: item = mtp*8 + mt2*4 + q; unique (item,col) per lane per (mt2,c2)
    {
      const int it0 = mtp * 8 + q, it1 = mtp * 8 + 4 + q;
      float g00 = lrelu(a200[0]) + lrelu(a200[1]) + lrelu(a200[2]) + lrelu(a200[3]);
      float g01 = lrelu(a201[0]) + lrelu(a201[1]) + lrelu(a201[2]) + lrelu(a201[3]);
      float g10 = lrelu(a210[0]) + lrelu(a210[1]) + lrelu(a210[2]) + lrelu(a210[3]);
      float g11 = lrelu(a211[0]) + lrelu(a211[1]) + lrelu(a211[2]) + lrelu(a211[3]);
      int a00 = it0 * 136 + cb0 + n16, a01 = it0 * 136 + cb0 + 16 + n16;
      int a10 = it1 * 136 + cb0 + n16, a11 = it1 * 136 + cb0 + 16 + n16;
      featB[a00] = f2bf(bflo((unsigned)featB[a00]) + (float)refcntL[it0] * g00);
      featB[a01] = f2bf(bflo((unsigned)featB[a01]) + (float)refcntL[it0] * g01);
      featB[a10] = f2bf(bflo((unsigned)featB[a10]) + (float)refcntL[it1] * g10);
      featB[a11] = f2bf(bflo((unsigned)featB[a11]) + (float)refcntL[it1] * g11);
    }
    __syncthreads();
  }

  // ---------------- Phase D: inter_items (featB A-fragments cached in regs) ----------------
  {
    short8 w1f[4], w2f[4];
#pragma unroll
    for (int kt = 0; kt < 4; ++kt) {
      w1f[kt] = *(const short8*)(wsW + 131072 + col * 128 + kt * 32 + kb);
      w2f[kt] = *(const short8*)(wsW + 147456 + col * 128 + kt * 32 + kb);
    }
    const f32x4 b1q = *(const f32x4*)(i2ib1 + wid * 16 + q * 4);
    const float b2v = i2ib2[col];
    short8 xc[4];
#pragma unroll
    for (int kt = 0; kt < 4; ++kt)
      xc[kt] = *(const short8*)(featB + n16 * 136 + kt * 32 + kb);

    for (int u = 0; u < nvs; ++u) {
      const int iv = oiL[vslL[u]];
      f32x4 acc = b1q;
      for (int kt = 0; kt < 4; ++kt) acc = MFMA16(w1f[kt], xc[kt], acc);
      {
        float h0 = lrelu(acc[0]), h1 = lrelu(acc[1]);
        float h2 = lrelu(acc[2]), h3 = lrelu(acc[3]);
        uint2 pk; pk.x = pk2(h0, h1); pk.y = pk2(h2, h3);
        *(uint2*)(hidS + n16 * 136 + wid * 16 + q * 4) = pk;
      }
      __syncthreads();
      f32x4 acc2 = (f32x4){b2v, b2v, b2v, b2v};
      for (int kt = 0; kt < 4; ++kt) {
        short8 h = *(const short8*)(hidS + n16 * 136 + kt * 32 + kb);
        acc2 = MFMA16(h, w2f[kt], acc2);
      }
      // msgs summed per item with weight = (item==iv) ? 0 : refcnt[item]
      float part = 0.f;
#pragma unroll
      for (int r = 0; r < 4; ++r) {
        int item = q * 4 + r;
        float w = (item == iv) ? 0.0f : (float)refcntL[item];
        part += w * lrelu(acc2[r]);
      }
      part += __shfl_xor(part, 16);
      part += __shfl_xor(part, 32);
      if (q == 0) {
        int a = iv * 136 + col;
        featB[a] = f2bf(bflo((unsigned)featB[a]) + part);
      }
      __syncthreads();
      // refresh cached featB row iv (only lanes whose fragment row changed)
      if (n16 == iv) {
#pragma unroll
        for (int kt = 0; kt < 4; ++kt)
          xc[kt] = *(const short8*)(featB + n16 * 136 + kt * 32 + kb);
      }
    }
  }

  // ---------------- Phase E: infer_outfit + score ----------------
  if (tid < 128) {
    float sum = 0.0f;
    for (int u = 0; u < nvs; ++u)
      sum += bflo((unsigned)featB[oiL[vslL[u]] * 136 + tid]);
    float v = sum * o2sW[tid];
#pragma unroll
    for (int off = 1; off < 64; off <<= 1) v += __shfl_xor(v, off);
    if (lane == 0) redE[wid] = v;
  }
  __syncthreads();
  if (tid == 0) {
    float t = redE[0] + redE[1] + o2sb[0];
    out[o] = 1.0f / (1.0f + expf(-t));
  }

  // ---------------- Phase F: com_loss (symmetric: f<=g only, x2 off-diag) ----------------
  {
    const int n = tid >> 5, f = (tid >> 3) & 3, g = (tid >> 1) & 3, h = tid & 1;
    float dot = 0.0f;
    if (f <= g) {
      const float* pa = facL + n * 528 + f * 132 + h * 64;
      const float* pb = facL + n * 528 + g * 132 + h * 64;
      for (int i = 0; i < 16; ++i) {
        float4 a = *(const float4*)(pa + i * 4);
        float4 b = *(const float4*)(pb + i * 4);
        dot += a.x * b.x + a.y * b.y + a.z * b.z + a.w * b.w;
      }
    }
    dot += __shfl_xor(dot, 1);  // combine k-halves
    float v = dot - ((f == g) ? 1.0f : 0.0f);
    float wgt = (f == g) ? 1.0f : 2.0f;
    float sq = (h == 0 && f <= g && oiL[n] != -1) ? wgt * v * v : 0.0f;
#pragma unroll
    for (int off = 1; off < 64; off <<= 1) sq += __shfl_xor(sq, off);
    __syncthreads();  // E's redE read complete before overwrite
    if (lane == 0) redE[wid] = sq;
    __syncthreads();
    if (tid == 0) {
      float tot = 0.f;
#pragma unroll
      for (int w = 0; w < 8; ++w) tot += redE[w];
      atomicAdd(out + 2048, tot * (1.0f / 2048.0f));
    }
  }
}

extern "C" void kernel_launch(void* const* d_in, const int* in_sizes, int n_in,
                              void* d_out, int out_size, void* d_ws, size_t ws_size,
                              hipStream_t stream) {
  float* out = (float*)d_out;
  ushort* ws = (ushort*)d_ws;  // needs 320KB
  hipLaunchKernelGGL(prep_weights, dim3(640), dim3(256), 0, stream,
                     (const float*)d_in[4], (const float*)d_in[6],
                     (const float*)d_in[8], (const float*)d_in[10],
                     (const float*)d_in[12], (const float*)d_in[14],
                     (const float*)d_in[16], (const float*)d_in[18],
                     ws, out);
  hipLaunchKernelGGL(mfgn_kernel, dim3(2048), dim3(512), 0, stream,
                     (const int*)d_in[0],
                     (const float*)d_in[1],
                     (const int*)d_in[2],
                     // d_in[3] items_factors unused; weights via ws
                     (const float*)d_in[5], (const float*)d_in[7],
                     (const float*)d_in[9], (const float*)d_in[11],
                     (const float*)d_in[13], (const float*)d_in[15],
                     (const float*)d_in[17], (const float*)d_in[19],
                     (const float*)d_in[20], (const float*)d_in[21],
                     (const ushort*)ws,
                     out);
}

// Round 4
// 336.504 us; speedup vs baseline: 1.5463x; 1.5463x over previous
//
#include <hip/hip_runtime.h>
#include <hip/hip_bf16.h>
#include <math.h>

// MFGN forward, MI355X. One block (512 thr, 8 waves) per outfit.
// R17: BARRIER-CHAIN diet on the known-good R13 structure.
// Evidence trail: R16 (1 blk/CU from VGPR+AGPR>128) ran 412us vs R13's 237
// at 2 blk/CU -> latency-bound on the per-block serial chain; co-residency
// overlap is ~1.74x. LDS traffic/conflicts are NOT the limiter (R16 cut
// conflicts 36% with zero gain). So: keep the R13 residency envelope
// (2 blk/CU, 16-col wave tiling, separate prodS/hidS, modest regs) and cut
// barrier-delimited segments ~49 -> ~41:
//  - Phase B staging COL-PARTITIONED: wave wid stages k-cols [wid*16,+16)
//    of ALL 64 prod rows. facL epilogue update is col-owned by the same
//    wave, and same-wave DS ops are ordered -> update->stage needs NO
//    barrier. Staging fuses into the L2 segment: 2 barriers/step (was 3).
//  - Phase B's last iteration stages Phase C's prod (bf16 copy of facL,
//    col-partitioned) -> C loses its staging segment + barrier.
//  - Phase D: featB A-fragments cached in regs (R16-proven), reload only
//    lanes n16==iv after the row update.
//  - Phase F: symmetric f<=g with x2 off-diag (R16-proven).
// launch_bounds(512,2): cap 128 regs -> no spill (R14 lesson), 2 blk/CU.
// R13 heritage: lrelu=fmax(x,.01x), bias-in-acc init, no conditional accs.

typedef __attribute__((ext_vector_type(8))) short short8;
typedef __attribute__((ext_vector_type(4))) float f32x4;

#define MFMA16(a, b, c) __builtin_amdgcn_mfma_f32_16x16x32_bf16(a, b, c, 0, 0, 0)

__device__ __forceinline__ float lrelu(float x) { return fmaxf(x, 0.01f * x); }

__device__ __forceinline__ ushort f2bf(float f) {
  unsigned u = __builtin_bit_cast(unsigned, f);
  u += 0x7fffu + ((u >> 16) & 1u);  // RNE
  return (ushort)(u >> 16);
}
__device__ __forceinline__ float bflo(unsigned u) {
  return __builtin_bit_cast(float, u << 16);
}
__device__ __forceinline__ unsigned pk2(float a, float b) {
  float2 t; t.x = a; t.y = b;
  __hip_bfloat162 h = __float22bfloat162_rn(t);
  unsigned u;
  __builtin_memcpy(&u, &h, 4);
  return u;
}

// d_ws layout (ushort): cfW1T@0 [4][64n][128k] | cfW2T@32768 [4][128n][64k]
// | f2fW1T@65536 | f2fW2T@81920 | f2iW1T@98304 | f2iW2T@114688
// | i2iW1T@131072 | i2iW2T@147456   ([128n][128k] each; 320KB total)

__global__ __launch_bounds__(256) void prep_weights(
    const float* __restrict__ cfW1, const float* __restrict__ cfW2,
    const float* __restrict__ f2fW1, const float* __restrict__ f2fW2,
    const float* __restrict__ f2iW1, const float* __restrict__ f2iW2,
    const float* __restrict__ i2iW1, const float* __restrict__ i2iW2,
    ushort* __restrict__ ws, float* __restrict__ out) {
  const int idx = (int)(blockIdx.x * 256 + threadIdx.x);
  if (idx == 0) out[2048] = 0.0f;  // com accumulator zero
  float v;
  if (idx < 32768) {          // cfW1 [f][k<128][n<64] -> [f][n][k]
    int f = idx >> 13, r = idx & 8191, n = r >> 7, k = r & 127;
    v = cfW1[f * 8192 + k * 64 + n];
  } else if (idx < 65536) {   // cfW2 [f][k<64][n<128] -> [f][n][k]
    int t = idx - 32768;
    int f = t >> 13, r = t & 8191, n = r >> 6, k = r & 63;
    v = cfW2[f * 8192 + k * 128 + n];
  } else {                    // 6 x [k<128][n<128] -> [n][k]
    int t = idx - 65536;
    int seg = t >> 14, r = t & 16383, n = r >> 7, k = r & 127;
    const float* W = (seg == 0) ? f2fW1 : (seg == 1) ? f2fW2 :
                     (seg == 2) ? f2iW1 : (seg == 3) ? f2iW2 :
                     (seg == 4) ? i2iW1 : i2iW2;
    v = W[k * 128 + n];
  }
  ws[idx] = f2bf(v);
}

__global__ __launch_bounds__(512, 2) void mfgn_kernel(
    const int* __restrict__ outfit_items,
    const float* __restrict__ items_feature,
    const int* __restrict__ items_neighbor,
    const float* __restrict__ cfb1, const float* __restrict__ cfb2,
    const float* __restrict__ f2fb1, const float* __restrict__ f2fb2,
    const float* __restrict__ f2ib1, const float* __restrict__ f2ib2,
    const float* __restrict__ i2ib1, const float* __restrict__ i2ib2,
    const float* __restrict__ o2sW, const float* __restrict__ o2sb,
    const ushort* __restrict__ wsW,
    float* __restrict__ out)
{
  __shared__ float facL[16 * 528];                                 // 33792 B fp32 state
  __shared__ ushort prodS[64 * 136] __attribute__((aligned(16)));  // 17408 B bf16 A-staging
  __shared__ ushort hidS[64 * 136] __attribute__((aligned(16)));   // 17408 B bf16 hidden
  __shared__ ushort featB[16 * 136] __attribute__((aligned(16)));  //  4352 B bf16 feat state
  __shared__ float redE[8];
  __shared__ int oiL[16];
  __shared__ int clAll[256];
  __shared__ int ncAll[16];
  __shared__ int vslL[16];
  __shared__ int refcntL[16];
  __shared__ int nvsL;

  const int o = blockIdx.x;
  const int tid = (int)threadIdx.x;
  const int lane = tid & 63;
  const int wid = tid >> 6;        // wave owns output cols wid*16..+15
  const int n16 = lane & 15;
  const int q = lane >> 4;
  const int kb = q * 8;
  const int col = wid * 16 + n16;
  // col-partitioned staging: lane <-> prod row (row = lane), wave owns
  // k-cols [wid*16, wid*16+16)
  const int fS = lane & 3, ciS = lane >> 2;
  const int kc0 = wid * 16;

  // ---------------- load inputs ----------------
  if (tid < 16) oiL[tid] = outfit_items[o * 16 + tid];
  {
    const int n = tid >> 5, d0 = (tid & 31) * 4;
    float4 v = *(const float4*)(items_feature + o * 2048 + tid * 4);
    uint2 pk; pk.x = pk2(v.x, v.y); pk.y = pk2(v.z, v.w);
    *(uint2*)(featB + n * 136 + d0) = pk;
  }
  if (tid == 0) {
    int cnt = 0;
    for (int s = 0; s < 16; ++s) refcntL[s] = 0;
    for (int s = 0; s < 16; ++s) {
      int v = oiL[s];
      if (v != -1) { vslL[cnt++] = s; refcntL[v]++; }
    }
    nvsL = cnt;
  }
  for (int s = wid; s < 16; s += 8) {
    const int iv = outfit_items[o * 16 + s];
    if (iv == -1) { if (lane == 0) ncAll[s] = 0; continue; }
    int cand = -1;
    if (lane < 24) cand = (lane < 16) ? outfit_items[o * 16 + lane]
                                      : items_neighbor[o * 128 + iv * 8 + (lane - 16)];
    bool ok = (lane < 24) && (cand != -1) && (cand != iv);
    unsigned long long bm = __ballot(ok);
    if (ok) clAll[s * 16 + __popcll(bm & ((1ull << lane) - 1ull))] = cand;
    if (lane == 0) ncAll[s] = (int)__popcll(bm);
  }
  __syncthreads();
  const int nvs = nvsL;

  // ---------------- Phase A: creat_factors ----------------
  {
    const int f = wid & 3, half = wid >> 2;
    short8 wA[2][4];
#pragma unroll
    for (int etl = 0; etl < 2; ++etl)
#pragma unroll
      for (int kt = 0; kt < 4; ++kt)
        wA[etl][kt] = *(const short8*)(wsW + (f * 64 + (half * 2 + etl) * 16 + n16) * 128
                                       + kt * 32 + kb);
    f32x4 acc[2];
#pragma unroll
    for (int etl = 0; etl < 2; ++etl)
      acc[etl] = *(const f32x4*)(cfb1 + f * 64 + (half * 2 + etl) * 16 + q * 4);  // bias init
    for (int kt = 0; kt < 4; ++kt) {
      short8 x = *(const short8*)(featB + n16 * 136 + kt * 32 + kb);
      acc[0] = MFMA16(wA[0][kt], x, acc[0]);
      acc[1] = MFMA16(wA[1][kt], x, acc[1]);
    }
#pragma unroll
    for (int etl = 0; etl < 2; ++etl) {
      float h0 = lrelu(acc[etl][0]), h1 = lrelu(acc[etl][1]);
      float h2 = lrelu(acc[etl][2]), h3 = lrelu(acc[etl][3]);
      uint2 pk; pk.x = pk2(h0, h1); pk.y = pk2(h2, h3);
      *(uint2*)(hidS + (f * 16 + n16) * 136 + (half * 2 + etl) * 16 + q * 4) = pk;
    }
    __syncthreads();
    short8 wB[4][2];
#pragma unroll
    for (int ctl = 0; ctl < 4; ++ctl)
#pragma unroll
      for (int kt = 0; kt < 2; ++kt)
        wB[ctl][kt] = *(const short8*)(wsW + 32768 + (f * 128 + half * 64 + ctl * 16 + n16) * 64
                                       + kt * 32 + kb);
    f32x4 acc2[4];
#pragma unroll
    for (int ctl = 0; ctl < 4; ++ctl) {
      float b2 = cfb2[f * 128 + half * 64 + ctl * 16 + n16];
      acc2[ctl] = (f32x4){b2, b2, b2, b2};  // bias init
    }
    for (int kt = 0; kt < 2; ++kt) {
      short8 h = *(const short8*)(hidS + (f * 16 + n16) * 136 + kt * 32 + kb);
#pragma unroll
      for (int ctl = 0; ctl < 4; ++ctl) acc2[ctl] = MFMA16(h, wB[ctl][kt], acc2[ctl]);
    }
#pragma unroll
    for (int ctl = 0; ctl < 4; ++ctl) {
      int c = half * 64 + ctl * 16 + n16;
#pragma unroll
      for (int r = 0; r < 4; ++r)
        facL[(q * 4 + r) * 528 + f * 132 + c] = lrelu(acc2[ctl][r]);
    }
    __syncthreads();
  }

  // ---------------- Phase B: inter_factors (2 barriers/step) ----------------
  {
    short8 w1f[4], w2f[4];
#pragma unroll
    for (int kt = 0; kt < 4; ++kt) {
      w1f[kt] = *(const short8*)(wsW + 65536 + col * 128 + kt * 32 + kb);
      w2f[kt] = *(const short8*)(wsW + 81920 + col * 128 + kt * 32 + kb);
    }
    const f32x4 b1q = *(const f32x4*)(f2fb1 + wid * 16 + q * 4);
    const float b2v = f2fb2[col];

    // stage product rows for slot s: prod[lane][kc0..+16) =
    //   bf16(fac[iv][fS][k] * fac[cand][fS][k]) (this wave's cols only)
    auto stageB = [&](int s, int iv_, int nc_) {
      if (ciS < nc_) {
        const int cit = clAll[s * 16 + ciS];
        const float* tp = facL + iv_ * 528 + fS * 132 + kc0;
        const float* cp = facL + cit * 528 + fS * 132 + kc0;
#pragma unroll
        for (int i2 = 0; i2 < 2; ++i2) {
          float4 a0 = *(const float4*)(tp + i2 * 8), a1 = *(const float4*)(tp + i2 * 8 + 4);
          float4 c0 = *(const float4*)(cp + i2 * 8), c1 = *(const float4*)(cp + i2 * 8 + 4);
          uint4 u4;
          u4.x = pk2(a0.x * c0.x, a0.y * c0.y); u4.y = pk2(a0.z * c0.z, a0.w * c0.w);
          u4.z = pk2(a1.x * c1.x, a1.y * c1.y); u4.w = pk2(a1.z * c1.z, a1.w * c1.w);
          *(uint4*)(prodS + lane * 136 + kc0 + i2 * 8) = u4;
        }
      }
      // rows >= 4*nc stale: finite bf16, epilogue-masked (MLP row-separable)
    };
    // stage Phase C's input: prod[lane][kc0..+16) = bf16(fac[item=ciS][fS][k])
    auto stageC = [&]() {
      const float* sp = facL + ciS * 528 + fS * 132 + kc0;
#pragma unroll
      for (int i2 = 0; i2 < 2; ++i2) {
        float4 a0 = *(const float4*)(sp + i2 * 8), a1 = *(const float4*)(sp + i2 * 8 + 4);
        uint4 u4;
        u4.x = pk2(a0.x, a0.y); u4.y = pk2(a0.z, a0.w);
        u4.z = pk2(a1.x, a1.y); u4.w = pk2(a1.z, a1.w);
        *(uint4*)(prodS + lane * 136 + kc0 + i2 * 8) = u4;
      }
    };

    if (nvs > 0) { const int s0 = vslL[0]; stageB(s0, oiL[s0], ncAll[s0]); }
    __syncthreads();  // [b1] products for step 0 ready

    for (int u = 0; u < nvs; ++u) {
      const int s = vslL[u];
      const int iv = oiL[s];
      const int nc = ncAll[s];
      // L1 swapped: unrolled 4 tiles, bias-initialized acc
      f32x4 acc[4];
#pragma unroll
      for (int mt = 0; mt < 4; ++mt) acc[mt] = b1q;
      for (int kt = 0; kt < 4; ++kt)
#pragma unroll
        for (int mt = 0; mt < 4; ++mt) {
          short8 x = *(const short8*)(prodS + (mt * 16 + n16) * 136 + kt * 32 + kb);
          acc[mt] = MFMA16(w1f[kt], x, acc[mt]);
        }
#pragma unroll
      for (int mt = 0; mt < 4; ++mt) {
        float h0 = lrelu(acc[mt][0]), h1 = lrelu(acc[mt][1]);
        float h2 = lrelu(acc[mt][2]), h3 = lrelu(acc[mt][3]);
        uint2 pk; pk.x = pk2(h0, h1); pk.y = pk2(h2, h3);
        *(uint2*)(hidS + (mt * 16 + n16) * 136 + wid * 16 + q * 4) = pk;
      }
      __syncthreads();  // [b2] hid ready
      // L2 normal: unrolled 4 tiles, bias-initialized acc
      f32x4 acc2[4];
#pragma unroll
      for (int mt = 0; mt < 4; ++mt) acc2[mt] = (f32x4){b2v, b2v, b2v, b2v};
      for (int kt = 0; kt < 4; ++kt)
#pragma unroll
        for (int mt = 0; mt < 4; ++mt) {
          short8 h = *(const short8*)(hidS + (mt * 16 + n16) * 136 + kt * 32 + kb);
          acc2[mt] = MFMA16(h, w2f[kt], acc2[mt]);
        }
      // epilogue: rows ci*4+f (f=reg); mask ci=mt*4+q<nc; sum over ci
      float part[4] = {0.f, 0.f, 0.f, 0.f};
#pragma unroll
      for (int mt = 0; mt < 4; ++mt) {
        bool act = (mt * 4 + q) < nc;
        if (act) {
#pragma unroll
          for (int r = 0; r < 4; ++r) part[r] += lrelu(acc2[mt][r]);
        }
      }
#pragma unroll
      for (int r = 0; r < 4; ++r) {
        float v = part[r];
        v += __shfl_xor(v, 16);
        v += __shfl_xor(v, 32);
        part[r] = v;
      }
      if (q == 0) {  // wave owns cols exclusively -> plain fp32 +=
#pragma unroll
        for (int r = 0; r < 4; ++r)
          facL[iv * 528 + r * 132 + col] += part[r];
      }
      // fused next-stage: update above touched only this wave's cols, and
      // staging reads only this wave's cols -> same-wave DS order suffices,
      // NO barrier between update and stage.
      if (u + 1 < nvs) {
        const int s2 = vslL[u + 1];
        stageB(s2, oiL[s2], ncAll[s2]);
      } else {
        stageC();
      }
      __syncthreads();  // [b1] next products (or Phase C input) ready
    }
    if (nvs == 0) { stageC(); __syncthreads(); }  // robustness (unused outputs)
  }

  // ---------------- Phase C: infer_items (input pre-staged by B) ----------------
  {
    short8 w1f[4], w2f[4];
#pragma unroll
    for (int kt = 0; kt < 4; ++kt) {
      w1f[kt] = *(const short8*)(wsW + 98304 + col * 128 + kt * 32 + kb);
      w2f[kt] = *(const short8*)(wsW + 114688 + col * 128 + kt * 32 + kb);
    }
    const f32x4 b1q = *(const f32x4*)(f2ib1 + wid * 16 + q * 4);
    const float b2v = f2ib2[col];
    f32x4 acc[4];
#pragma unroll
    for (int mt = 0; mt < 4; ++mt) acc[mt] = b1q;
    for (int kt = 0; kt < 4; ++kt)
#pragma unroll
      for (int mt = 0; mt < 4; ++mt) {
        short8 x = *(const short8*)(prodS + (mt * 16 + n16) * 136 + kt * 32 + kb);
        acc[mt] = MFMA16(w1f[kt], x, acc[mt]);
      }
#pragma unroll
    for (int mt = 0; mt < 4; ++mt) {
      float h0 = lrelu(acc[mt][0]), h1 = lrelu(acc[mt][1]);
      float h2 = lrelu(acc[mt][2]), h3 = lrelu(acc[mt][3]);
      uint2 pk; pk.x = pk2(h0, h1); pk.y = pk2(h2, h3);
      *(uint2*)(hidS + (mt * 16 + n16) * 136 + wid * 16 + q * 4) = pk;
    }
    __syncthreads();
    f32x4 acc2[4];
#pragma unroll
    for (int mt = 0; mt < 4; ++mt) acc2[mt] = (f32x4){b2v, b2v, b2v, b2v};
    for (int kt = 0; kt < 4; ++kt)
#pragma unroll
      for (int mt = 0; mt < 4; ++mt) {
        short8 h = *(const short8*)(hidS + (mt * 16 + n16) * 136 + kt * 32 + kb);
        acc2[mt] = MFMA16(h, w2f[kt], acc2[mt]);
      }
#pragma unroll
    for (int mt = 0; mt < 4; ++mt) {
      int item = mt * 4 + q;  // rows = item*4+f, f=reg
      float g = 0.f;
#pragma unroll
      for (int r = 0; r < 4; ++r) g += lrelu(acc2[mt][r]);
      int a = item * 136 + col;  // unique (item,col) per lane
      featB[a] = f2bf(bflo((unsigned)featB[a]) + (float)refcntL[item] * g);
    }
    __syncthreads();
  }

  // ---------------- Phase D: inter_items (featB A-fragments reg-cached) ----------------
  {
    short8 w1f[4], w2f[4];
#pragma unroll
    for (int kt = 0; kt < 4; ++kt) {
      w1f[kt] = *(const short8*)(wsW + 131072 + col * 128 + kt * 32 + kb);
      w2f[kt] = *(const short8*)(wsW + 147456 + col * 128 + kt * 32 + kb);
    }
    const f32x4 b1q = *(const f32x4*)(i2ib1 + wid * 16 + q * 4);
    const float b2v = i2ib2[col];
    short8 xc[4];
#pragma unroll
    for (int kt = 0; kt < 4; ++kt)
      xc[kt] = *(const short8*)(featB + n16 * 136 + kt * 32 + kb);

    for (int u = 0; u < nvs; ++u) {
      const int iv = oiL[vslL[u]];
      f32x4 acc = b1q;
      for (int kt = 0; kt < 4; ++kt) acc = MFMA16(w1f[kt], xc[kt], acc);
      {
        float h0 = lrelu(acc[0]), h1 = lrelu(acc[1]);
        float h2 = lrelu(acc[2]), h3 = lrelu(acc[3]);
        uint2 pk; pk.x = pk2(h0, h1); pk.y = pk2(h2, h3);
        *(uint2*)(hidS + n16 * 136 + wid * 16 + q * 4) = pk;
      }
      __syncthreads();
      f32x4 acc2 = (f32x4){b2v, b2v, b2v, b2v};
      for (int kt = 0; kt < 4; ++kt) {
        short8 h = *(const short8*)(hidS + n16 * 136 + kt * 32 + kb);
        acc2 = MFMA16(h, w2f[kt], acc2);
      }
      // msgs summed per item with weight = (item==iv) ? 0 : refcnt[item]
      float part = 0.f;
#pragma unroll
      for (int r = 0; r < 4; ++r) {
        int item = q * 4 + r;
        float w = (item == iv) ? 0.0f : (float)refcntL[item];
        part += w * lrelu(acc2[r]);
      }
      part += __shfl_xor(part, 16);
      part += __shfl_xor(part, 32);
      if (q == 0) {
        int a = iv * 136 + col;
        featB[a] = f2bf(bflo((unsigned)featB[a]) + part);
      }
      __syncthreads();
      // refresh cached featB row iv (only lanes whose fragment row changed);
      // next update happens only after the next barrier -> no race
      if (n16 == iv) {
#pragma unroll
        for (int kt = 0; kt < 4; ++kt)
          xc[kt] = *(const short8*)(featB + n16 * 136 + kt * 32 + kb);
      }
    }
  }

  // ---------------- Phase E: infer_outfit + score ----------------
  if (tid < 128) {
    float sum = 0.0f;
    for (int u = 0; u < nvs; ++u)
      sum += bflo((unsigned)featB[oiL[vslL[u]] * 136 + tid]);
    float v = sum * o2sW[tid];
#pragma unroll
    for (int off = 1; off < 64; off <<= 1) v += __shfl_xor(v, off);
    if (lane == 0) redE[wid] = v;
  }
  __syncthreads();
  if (tid == 0) {
    float t = redE[0] + redE[1] + o2sb[0];
    out[o] = 1.0f / (1.0f + expf(-t));
  }

  // ---------------- Phase F: com_loss (symmetric: f<=g only, x2 off-diag) ----------------
  {
    const int n = tid >> 5, f = (tid >> 3) & 3, g = (tid >> 1) & 3, h = tid & 1;
    float dot = 0.0f;
    if (f <= g) {
      const float* pa = facL + n * 528 + f * 132 + h * 64;
      const float* pb = facL + n * 528 + g * 132 + h * 64;
      for (int i = 0; i < 16; ++i) {
        float4 a = *(const float4*)(pa + i * 4);
        float4 b = *(const float4*)(pb + i * 4);
        dot += a.x * b.x + a.y * b.y + a.z * b.z + a.w * b.w;
      }
    }
    dot += __shfl_xor(dot, 1);  // combine k-halves
    float v = dot - ((f == g) ? 1.0f : 0.0f);
    float wgt = (f == g) ? 1.0f : 2.0f;
    float sq = (h == 0 && f <= g && oiL[n] != -1) ? wgt * v * v : 0.0f;
#pragma unroll
    for (int off = 1; off < 64; off <<= 1) sq += __shfl_xor(sq, off);
    __syncthreads();  // E's redE read complete before overwrite
    if (lane == 0) redE[wid] = sq;
    __syncthreads();
    if (tid == 0) {
      float tot = 0.f;
#pragma unroll
      for (int w = 0; w < 8; ++w) tot += redE[w];
      atomicAdd(out + 2048, tot * (1.0f / 2048.0f));
    }
  }
}

extern "C" void kernel_launch(void* const* d_in, const int* in_sizes, int n_in,
                              void* d_out, int out_size, void* d_ws, size_t ws_size,
                              hipStream_t stream) {
  float* out = (float*)d_out;
  ushort* ws = (ushort*)d_ws;  // needs 320KB
  hipLaunchKernelGGL(prep_weights, dim3(640), dim3(256), 0, stream,
                     (const float*)d_in[4], (const float*)d_in[6],
                     (const float*)d_in[8], (const float*)d_in[10],
                     (const float*)d_in[12], (const float*)d_in[14],
                     (const float*)d_in[16], (const float*)d_in[18],
                     ws, out);
  hipLaunchKernelGGL(mfgn_kernel, dim3(2048), dim3(512), 0, stream,
                     (const int*)d_in[0],
                     (const float*)d_in[1],
                     (const int*)d_in[2],
                     // d_in[3] items_factors unused; weights via ws
                     (const float*)d_in[5], (const float*)d_in[7],
                     (const float*)d_in[9], (const float*)d_in[11],
                     (const float*)d_in[13], (const float*)d_in[15],
                     (const float*)d_in[17], (const float*)d_in[19],
                     (const float*)d_in[20], (const float*)d_in[21],
                     (const ushort*)ws,
                     out);
}

// Round 5
// 320.861 us; speedup vs baseline: 1.6217x; 1.0488x over previous
//
#include <hip/hip_runtime.h>
#include <hip/hip_bf16.h>
#include <math.h>

// MFGN forward, MI355X. One block (512 thr, 8 waves) per outfit.
// R18: FRAGMENT-MAJOR LDS layout (conflict elimination).
// Evidence: conflicts = 2.9e7 (~20% of wall/CU); bank algebra shows the
// row-major [64][136] tiles give 8-way conflicts on ALL fragment reads
// (row stride 272B = 4-bank shift -> 64 lanes on 8 slots) and pad/XOR
// provably cannot fix it. New layout: prodS/hidS/featB stored as MFMA
// fragments: 16B unit (mt,kt,lane) at (kt*4+mt)*512 + lane*8 ushorts ->
// fragment read = base + lane*16B = canonical conflict-free; staging
// writes = 16-lane contiguous 256B runs. Same instruction counts.
// Kept from R17: 2 blk/CU envelope (hidden AGPRs forbid 3 blocks - R15),
// col-partitioned staging fused after facL update (2 barriers/B-step),
// B's last iter pre-stages C, D reg-cached featB, F symmetric.
// R13 heritage: lrelu=fmax(x,.01x), bias-in-acc init, no conditional accs.

typedef __attribute__((ext_vector_type(8))) short short8;
typedef __attribute__((ext_vector_type(4))) float f32x4;

#define MFMA16(a, b, c) __builtin_amdgcn_mfma_f32_16x16x32_bf16(a, b, c, 0, 0, 0)

__device__ __forceinline__ float lrelu(float x) { return fmaxf(x, 0.01f * x); }

__device__ __forceinline__ ushort f2bf(float f) {
  unsigned u = __builtin_bit_cast(unsigned, f);
  u += 0x7fffu + ((u >> 16) & 1u);  // RNE
  return (ushort)(u >> 16);
}
__device__ __forceinline__ float bflo(unsigned u) {
  return __builtin_bit_cast(float, u << 16);
}
__device__ __forceinline__ unsigned pk2(float a, float b) {
  float2 t; t.x = a; t.y = b;
  __hip_bfloat162 h = __float22bfloat162_rn(t);
  unsigned u;
  __builtin_memcpy(&u, &h, 4);
  return u;
}

// d_ws layout (ushort): cfW1T@0 [4][64n][128k] | cfW2T@32768 [4][128n][64k]
// | f2fW1T@65536 | f2fW2T@81920 | f2iW1T@98304 | f2iW2T@114688
// | i2iW1T@131072 | i2iW2T@147456   ([128n][128k] each; 320KB total)

__global__ __launch_bounds__(256) void prep_weights(
    const float* __restrict__ cfW1, const float* __restrict__ cfW2,
    const float* __restrict__ f2fW1, const float* __restrict__ f2fW2,
    const float* __restrict__ f2iW1, const float* __restrict__ f2iW2,
    const float* __restrict__ i2iW1, const float* __restrict__ i2iW2,
    ushort* __restrict__ ws, float* __restrict__ out) {
  const int idx = (int)(blockIdx.x * 256 + threadIdx.x);
  if (idx == 0) out[2048] = 0.0f;  // com accumulator zero
  float v;
  if (idx < 32768) {          // cfW1 [f][k<128][n<64] -> [f][n][k]
    int f = idx >> 13, r = idx & 8191, n = r >> 7, k = r & 127;
    v = cfW1[f * 8192 + k * 64 + n];
  } else if (idx < 65536) {   // cfW2 [f][k<64][n<128] -> [f][n][k]
    int t = idx - 32768;
    int f = t >> 13, r = t & 8191, n = r >> 6, k = r & 63;
    v = cfW2[f * 8192 + k * 128 + n];
  } else {                    // 6 x [k<128][n<128] -> [n][k]
    int t = idx - 65536;
    int seg = t >> 14, r = t & 16383, n = r >> 7, k = r & 127;
    const float* W = (seg == 0) ? f2fW1 : (seg == 1) ? f2fW2 :
                     (seg == 2) ? f2iW1 : (seg == 3) ? f2iW2 :
                     (seg == 4) ? i2iW1 : i2iW2;
    v = W[k * 128 + n];
  }
  ws[idx] = f2bf(v);
}

__global__ __launch_bounds__(512, 2) void mfgn_kernel(
    const int* __restrict__ outfit_items,
    const float* __restrict__ items_feature,
    const int* __restrict__ items_neighbor,
    const float* __restrict__ cfb1, const float* __restrict__ cfb2,
    const float* __restrict__ f2fb1, const float* __restrict__ f2fb2,
    const float* __restrict__ f2ib1, const float* __restrict__ f2ib2,
    const float* __restrict__ i2ib1, const float* __restrict__ i2ib2,
    const float* __restrict__ o2sW, const float* __restrict__ o2sb,
    const ushort* __restrict__ wsW,
    float* __restrict__ out)
{
  __shared__ float facL[16 * 528];                                // 33792 B fp32 state
  __shared__ ushort prodS[8192] __attribute__((aligned(16)));     // 16 frags (mt,kt)
  __shared__ ushort hidS[8192] __attribute__((aligned(16)));      // 16 frags (mt,kt)
  __shared__ ushort featB[2048] __attribute__((aligned(16)));     // 4 frags (kt), 16 rows
  __shared__ float redE[8];
  __shared__ int oiL[16];
  __shared__ int clAll[256];
  __shared__ int ncAll[16];
  __shared__ int vslL[16];
  __shared__ int refcntL[16];
  __shared__ int nvsL;
  // frag unit (mt,kt,l): 8 ushorts at (kt*4+mt)*512 + l*8.
  // unit holds X[row = mt*16 + (l&15)][k = kt*32 + (l>>4)*8 .. +8].
  // fragment read = base + lane*16B -> contiguous, conflict-free.
  // featB: 16 rows only -> units (kt): kt*512 + l*8.
  // element (row,c) lives at (c>>5)*512 + (((c>>3)&3)*16 + row)*8 + (c&7).

  const int o = blockIdx.x;
  const int tid = (int)threadIdx.x;
  const int lane = tid & 63;
  const int wid = tid >> 6;        // wave owns output cols wid*16..+15
  const int n16 = lane & 15;
  const int q = lane >> 4;
  const int kb = q * 8;
  const int col = wid * 16 + n16;
  const int lx = lane * 8;         // fragment lane offset (ushorts)
  // col-partitioned staging: lane = prod row; wave owns k-cols [wid*16,+16)
  const int fS = lane & 3, ciS = lane >> 2;
  const int kc0 = wid * 16;
  const int q0 = (wid & 1) * 2;    // staged k-chunks are q-slots q0,q0+1 of kt=wid>>1
  const int sWA = ((wid >> 1) * 4 + (lane >> 4)) * 512 + (lane & 15) * 8;
  // hid write base for B/C (add mt*512) and D (mt=0)
  const int hwB = (wid >> 1) * 2048 + ((wid & 1) * 2 + (q >> 1)) * 128 + n16 * 8 + (q & 1) * 4;
  // featB element base for this lane's col (add item*8)
  const int fbCol = (col >> 5) * 512 + ((col >> 3) & 3) * 128 + (col & 7);

  // ---------------- load inputs ----------------
  if (tid < 16) oiL[tid] = outfit_items[o * 16 + tid];
  {
    const int n = tid >> 5, d0 = (tid & 31) * 4;
    float4 v = *(const float4*)(items_feature + o * 2048 + tid * 4);
    uint2 pk; pk.x = pk2(v.x, v.y); pk.y = pk2(v.z, v.w);
    *(uint2*)(featB + (d0 >> 5) * 512 + (((d0 >> 3) & 3) * 16 + n) * 8 + (d0 & 7)) = pk;
  }
  if (tid == 0) {
    int cnt = 0;
    for (int s = 0; s < 16; ++s) refcntL[s] = 0;
    for (int s = 0; s < 16; ++s) {
      int v = oiL[s];
      if (v != -1) { vslL[cnt++] = s; refcntL[v]++; }
    }
    nvsL = cnt;
  }
  for (int s = wid; s < 16; s += 8) {
    const int iv = outfit_items[o * 16 + s];
    if (iv == -1) { if (lane == 0) ncAll[s] = 0; continue; }
    int cand = -1;
    if (lane < 24) cand = (lane < 16) ? outfit_items[o * 16 + lane]
                                      : items_neighbor[o * 128 + iv * 8 + (lane - 16)];
    bool ok = (lane < 24) && (cand != -1) && (cand != iv);
    unsigned long long bm = __ballot(ok);
    if (ok) clAll[s * 16 + __popcll(bm & ((1ull << lane) - 1ull))] = cand;
    if (lane == 0) ncAll[s] = (int)__popcll(bm);
  }
  __syncthreads();
  const int nvs = nvsL;

  // ---------------- Phase A: creat_factors ----------------
  {
    const int f = wid & 3, half = wid >> 2;
    short8 wA[2][4];
#pragma unroll
    for (int etl = 0; etl < 2; ++etl)
#pragma unroll
      for (int kt = 0; kt < 4; ++kt)
        wA[etl][kt] = *(const short8*)(wsW + (f * 64 + (half * 2 + etl) * 16 + n16) * 128
                                       + kt * 32 + kb);
    f32x4 acc[2];
#pragma unroll
    for (int etl = 0; etl < 2; ++etl)
      acc[etl] = *(const f32x4*)(cfb1 + f * 64 + (half * 2 + etl) * 16 + q * 4);  // bias init
    for (int kt = 0; kt < 4; ++kt) {
      short8 x = *(const short8*)(featB + kt * 512 + lx);
      acc[0] = MFMA16(wA[0][kt], x, acc[0]);
      acc[1] = MFMA16(wA[1][kt], x, acc[1]);
    }
#pragma unroll
    for (int etl = 0; etl < 2; ++etl) {
      float h0 = lrelu(acc[etl][0]), h1 = lrelu(acc[etl][1]);
      float h2 = lrelu(acc[etl][2]), h3 = lrelu(acc[etl][3]);
      uint2 pk; pk.x = pk2(h0, h1); pk.y = pk2(h2, h3);
      // hid row f*16+n16, cols (half*2+etl)*16 + q*4 .. +3 (D2=64, kt_h=half)
      *(uint2*)(hidS + half * 2048 + f * 512 + (etl * 2 + (q >> 1)) * 128
                + n16 * 8 + (q & 1) * 4) = pk;
    }
    __syncthreads();
    short8 wB[4][2];
#pragma unroll
    for (int ctl = 0; ctl < 4; ++ctl)
#pragma unroll
      for (int kt = 0; kt < 2; ++kt)
        wB[ctl][kt] = *(const short8*)(wsW + 32768 + (f * 128 + half * 64 + ctl * 16 + n16) * 64
                                       + kt * 32 + kb);
    f32x4 acc2[4];
#pragma unroll
    for (int ctl = 0; ctl < 4; ++ctl) {
      float b2 = cfb2[f * 128 + half * 64 + ctl * 16 + n16];
      acc2[ctl] = (f32x4){b2, b2, b2, b2};  // bias init
    }
    for (int kt = 0; kt < 2; ++kt) {
      short8 h = *(const short8*)(hidS + (kt * 4 + f) * 512 + lx);
#pragma unroll
      for (int ctl = 0; ctl < 4; ++ctl) acc2[ctl] = MFMA16(h, wB[ctl][kt], acc2[ctl]);
    }
#pragma unroll
    for (int ctl = 0; ctl < 4; ++ctl) {
      int c = half * 64 + ctl * 16 + n16;
#pragma unroll
      for (int r = 0; r < 4; ++r)
        facL[(q * 4 + r) * 528 + f * 132 + c] = lrelu(acc2[ctl][r]);
    }
    __syncthreads();
  }

  // ---------------- Phase B: inter_factors (2 barriers/step) ----------------
  {
    short8 w1f[4], w2f[4];
#pragma unroll
    for (int kt = 0; kt < 4; ++kt) {
      w1f[kt] = *(const short8*)(wsW + 65536 + col * 128 + kt * 32 + kb);
      w2f[kt] = *(const short8*)(wsW + 81920 + col * 128 + kt * 32 + kb);
    }
    const f32x4 b1q = *(const f32x4*)(f2fb1 + wid * 16 + q * 4);
    const float b2v = f2fb2[col];

    // stage prod rows for slot s into frag layout (this wave's k-cols only)
    auto stageB = [&](int s, int iv_, int nc_) {
      if (ciS < nc_) {
        const int cit = clAll[s * 16 + ciS];
        const float* tp = facL + iv_ * 528 + fS * 132 + kc0;
        const float* cp = facL + cit * 528 + fS * 132 + kc0;
#pragma unroll
        for (int g = 0; g < 2; ++g) {
          float4 a0 = *(const float4*)(tp + g * 8), a1 = *(const float4*)(tp + g * 8 + 4);
          float4 c0 = *(const float4*)(cp + g * 8), c1 = *(const float4*)(cp + g * 8 + 4);
          uint4 u4;
          u4.x = pk2(a0.x * c0.x, a0.y * c0.y); u4.y = pk2(a0.z * c0.z, a0.w * c0.w);
          u4.z = pk2(a1.x * c1.x, a1.y * c1.y); u4.w = pk2(a1.z * c1.z, a1.w * c1.w);
          *(uint4*)(prodS + sWA + (q0 + g) * 128) = u4;
        }
      }
      // rows >= 4*nc stale: finite bf16, epilogue-masked (MLP row-separable)
    };
    // stage Phase C's input: bf16(fac[item=ciS][fS][k]) in frag layout
    auto stageC = [&]() {
      const float* sp = facL + ciS * 528 + fS * 132 + kc0;
#pragma unroll
      for (int g = 0; g < 2; ++g) {
        float4 a0 = *(const float4*)(sp + g * 8), a1 = *(const float4*)(sp + g * 8 + 4);
        uint4 u4;
        u4.x = pk2(a0.x, a0.y); u4.y = pk2(a0.z, a0.w);
        u4.z = pk2(a1.x, a1.y); u4.w = pk2(a1.z, a1.w);
        *(uint4*)(prodS + sWA + (q0 + g) * 128) = u4;
      }
    };

    if (nvs > 0) { const int s0 = vslL[0]; stageB(s0, oiL[s0], ncAll[s0]); }
    __syncthreads();  // [b1] products for step 0 ready

    for (int u = 0; u < nvs; ++u) {
      const int s = vslL[u];
      const int iv = oiL[s];
      const int nc = ncAll[s];
      // L1 swapped: unrolled 4 tiles, bias-initialized acc
      f32x4 acc[4];
#pragma unroll
      for (int mt = 0; mt < 4; ++mt) acc[mt] = b1q;
      for (int kt = 0; kt < 4; ++kt)
#pragma unroll
        for (int mt = 0; mt < 4; ++mt) {
          short8 x = *(const short8*)(prodS + (kt * 4 + mt) * 512 + lx);
          acc[mt] = MFMA16(w1f[kt], x, acc[mt]);
        }
#pragma unroll
      for (int mt = 0; mt < 4; ++mt) {
        float h0 = lrelu(acc[mt][0]), h1 = lrelu(acc[mt][1]);
        float h2 = lrelu(acc[mt][2]), h3 = lrelu(acc[mt][3]);
        uint2 pk; pk.x = pk2(h0, h1); pk.y = pk2(h2, h3);
        *(uint2*)(hidS + hwB + mt * 512) = pk;
      }
      __syncthreads();  // [b2] hid ready
      // L2 normal: unrolled 4 tiles, bias-initialized acc
      f32x4 acc2[4];
#pragma unroll
      for (int mt = 0; mt < 4; ++mt) acc2[mt] = (f32x4){b2v, b2v, b2v, b2v};
      for (int kt = 0; kt < 4; ++kt)
#pragma unroll
        for (int mt = 0; mt < 4; ++mt) {
          short8 h = *(const short8*)(hidS + (kt * 4 + mt) * 512 + lx);
          acc2[mt] = MFMA16(h, w2f[kt], acc2[mt]);
        }
      // epilogue: rows ci*4+f (f=reg); mask ci=mt*4+q<nc; sum over ci
      float part[4] = {0.f, 0.f, 0.f, 0.f};
#pragma unroll
      for (int mt = 0; mt < 4; ++mt) {
        bool act = (mt * 4 + q) < nc;
        if (act) {
#pragma unroll
          for (int r = 0; r < 4; ++r) part[r] += lrelu(acc2[mt][r]);
        }
      }
#pragma unroll
      for (int r = 0; r < 4; ++r) {
        float v = part[r];
        v += __shfl_xor(v, 16);
        v += __shfl_xor(v, 32);
        part[r] = v;
      }
      if (q == 0) {  // wave owns cols exclusively -> plain fp32 +=
#pragma unroll
        for (int r = 0; r < 4; ++r)
          facL[iv * 528 + r * 132 + col] += part[r];
      }
      // fused next-stage: update touched only this wave's cols; staging
      // reads only this wave's cols -> same-wave DS order, NO barrier.
      if (u + 1 < nvs) {
        const int s2 = vslL[u + 1];
        stageB(s2, oiL[s2], ncAll[s2]);
      } else {
        stageC();
      }
      __syncthreads();  // [b1] next products (or Phase C input) ready
    }
    if (nvs == 0) { stageC(); __syncthreads(); }  // robustness (unused outputs)
  }

  // ---------------- Phase C: infer_items (input pre-staged by B) ----------------
  {
    short8 w1f[4], w2f[4];
#pragma unroll
    for (int kt = 0; kt < 4; ++kt) {
      w1f[kt] = *(const short8*)(wsW + 98304 + col * 128 + kt * 32 + kb);
      w2f[kt] = *(const short8*)(wsW + 114688 + col * 128 + kt * 32 + kb);
    }
    const f32x4 b1q = *(const f32x4*)(f2ib1 + wid * 16 + q * 4);
    const float b2v = f2ib2[col];
    f32x4 acc[4];
#pragma unroll
    for (int mt = 0; mt < 4; ++mt) acc[mt] = b1q;
    for (int kt = 0; kt < 4; ++kt)
#pragma unroll
      for (int mt = 0; mt < 4; ++mt) {
        short8 x = *(const short8*)(prodS + (kt * 4 + mt) * 512 + lx);
        acc[mt] = MFMA16(w1f[kt], x, acc[mt]);
      }
#pragma unroll
    for (int mt = 0; mt < 4; ++mt) {
      float h0 = lrelu(acc[mt][0]), h1 = lrelu(acc[mt][1]);
      float h2 = lrelu(acc[mt][2]), h3 = lrelu(acc[mt][3]);
      uint2 pk; pk.x = pk2(h0, h1); pk.y = pk2(h2, h3);
      *(uint2*)(hidS + hwB + mt * 512) = pk;
    }
    __syncthreads();
    f32x4 acc2[4];
#pragma unroll
    for (int mt = 0; mt < 4; ++mt) acc2[mt] = (f32x4){b2v, b2v, b2v, b2v};
    for (int kt = 0; kt < 4; ++kt)
#pragma unroll
      for (int mt = 0; mt < 4; ++mt) {
        short8 h = *(const short8*)(hidS + (kt * 4 + mt) * 512 + lx);
        acc2[mt] = MFMA16(h, w2f[kt], acc2[mt]);
      }
#pragma unroll
    for (int mt = 0; mt < 4; ++mt) {
      int item = mt * 4 + q;  // rows = item*4+f, f=reg
      float g = 0.f;
#pragma unroll
      for (int r = 0; r < 4; ++r) g += lrelu(acc2[mt][r]);
      int a = fbCol + item * 8;  // unique (item,col) per lane
      featB[a] = f2bf(bflo((unsigned)featB[a]) + (float)refcntL[item] * g);
    }
    __syncthreads();
  }

  // ---------------- Phase D: inter_items (featB A-fragments reg-cached) ----------------
  {
    short8 w1f[4], w2f[4];
#pragma unroll
    for (int kt = 0; kt < 4; ++kt) {
      w1f[kt] = *(const short8*)(wsW + 131072 + col * 128 + kt * 32 + kb);
      w2f[kt] = *(const short8*)(wsW + 147456 + col * 128 + kt * 32 + kb);
    }
    const f32x4 b1q = *(const f32x4*)(i2ib1 + wid * 16 + q * 4);
    const float b2v = i2ib2[col];
    short8 xc[4];
#pragma unroll
    for (int kt = 0; kt < 4; ++kt)
      xc[kt] = *(const short8*)(featB + kt * 512 + lx);

    for (int u = 0; u < nvs; ++u) {
      const int iv = oiL[vslL[u]];
      f32x4 acc = b1q;
      for (int kt = 0; kt < 4; ++kt) acc = MFMA16(w1f[kt], xc[kt], acc);
      {
        float h0 = lrelu(acc[0]), h1 = lrelu(acc[1]);
        float h2 = lrelu(acc[2]), h3 = lrelu(acc[3]);
        uint2 pk; pk.x = pk2(h0, h1); pk.y = pk2(h2, h3);
        *(uint2*)(hidS + hwB) = pk;   // rows n16 -> mt=0 frags
      }
      __syncthreads();
      f32x4 acc2 = (f32x4){b2v, b2v, b2v, b2v};
      for (int kt = 0; kt < 4; ++kt) {
        short8 h = *(const short8*)(hidS + kt * 2048 + lx);
        acc2 = MFMA16(h, w2f[kt], acc2);
      }
      // msgs summed per item with weight = (item==iv) ? 0 : refcnt[item]
      float part = 0.f;
#pragma unroll
      for (int r = 0; r < 4; ++r) {
        int item = q * 4 + r;
        float w = (item == iv) ? 0.0f : (float)refcntL[item];
        part += w * lrelu(acc2[r]);
      }
      part += __shfl_xor(part, 16);
      part += __shfl_xor(part, 32);
      if (q == 0) {
        int a = fbCol + iv * 8;
        featB[a] = f2bf(bflo((unsigned)featB[a]) + part);
      }
      __syncthreads();
      // refresh cached featB row iv (only lanes whose fragment row changed);
      // next update happens only after the next barrier -> no race
      if (n16 == iv) {
#pragma unroll
        for (int kt = 0; kt < 4; ++kt)
          xc[kt] = *(const short8*)(featB + kt * 512 + lx);
      }
    }
  }

  // ---------------- Phase E: infer_outfit + score ----------------
  if (tid < 128) {
    const int eb = (tid >> 5) * 512 + ((tid >> 3) & 3) * 128 + (tid & 7);
    float sum = 0.0f;
    for (int u = 0; u < nvs; ++u) {
      int it = oiL[vslL[u]];
      sum += bflo((unsigned)featB[eb + it * 8]);
    }
    float v = sum * o2sW[tid];
#pragma unroll
    for (int off = 1; off < 64; off <<= 1) v += __shfl_xor(v, off);
    if (lane == 0) redE[wid] = v;
  }
  __syncthreads();
  if (tid == 0) {
    float t = redE[0] + redE[1] + o2sb[0];
    out[o] = 1.0f / (1.0f + expf(-t));
  }

  // ---------------- Phase F: com_loss (symmetric: f<=g only, x2 off-diag) ----------------
  {
    const int n = tid >> 5, f = (tid >> 3) & 3, g = (tid >> 1) & 3, h = tid & 1;
    float dot = 0.0f;
    if (f <= g) {
      const float* pa = facL + n * 528 + f * 132 + h * 64;
      const float* pb = facL + n * 528 + g * 132 + h * 64;
      for (int i = 0; i < 16; ++i) {
        float4 a = *(const float4*)(pa + i * 4);
        float4 b = *(const float4*)(pb + i * 4);
        dot += a.x * b.x + a.y * b.y + a.z * b.z + a.w * b.w;
      }
    }
    dot += __shfl_xor(dot, 1);  // combine k-halves
    float v = dot - ((f == g) ? 1.0f : 0.0f);
    float wgt = (f == g) ? 1.0f : 2.0f;
    float sq = (h == 0 && f <= g && oiL[n] != -1) ? wgt * v * v : 0.0f;
#pragma unroll
    for (int off = 1; off < 64; off <<= 1) sq += __shfl_xor(sq, off);
    __syncthreads();  // E's redE read complete before overwrite
    if (lane == 0) redE[wid] = sq;
    __syncthreads();
    if (tid == 0) {
      float tot = 0.f;
#pragma unroll
      for (int w = 0; w < 8; ++w) tot += redE[w];
      atomicAdd(out + 2048, tot * (1.0f / 2048.0f));
    }
  }
}

extern "C" void kernel_launch(void* const* d_in, const int* in_sizes, int n_in,
                              void* d_out, int out_size, void* d_ws, size_t ws_size,
                              hipStream_t stream) {
  float* out = (float*)d_out;
  ushort* ws = (ushort*)d_ws;  // needs 320KB
  hipLaunchKernelGGL(prep_weights, dim3(640), dim3(256), 0, stream,
                     (const float*)d_in[4], (const float*)d_in[6],
                     (const float*)d_in[8], (const float*)d_in[10],
                     (const float*)d_in[12], (const float*)d_in[14],
                     (const float*)d_in[16], (const float*)d_in[18],
                     ws, out);
  hipLaunchKernelGGL(mfgn_kernel, dim3(2048), dim3(512), 0, stream,
                     (const int*)d_in[0],
                     (const float*)d_in[1],
                     (const int*)d_in[2],
                     // d_in[3] items_factors unused; weights via ws
                     (const float*)d_in[5], (const float*)d_in[7],
                     (const float*)d_in[9], (const float*)d_in[11],
                     (const float*)d_in[13], (const float*)d_in[15],
                     (const float*)d_in[17], (const float*)d_in[19],
                     (const float*)d_in[20], (const float*)d_in[21],
                     (const ushort*)ws,
                     out);
}